// Round 4
// baseline (956.275 us; speedup 1.0000x reference)
//
#include <hip/hip_runtime.h>
#include <math.h>

// Problem constants: B=2, S=1024 -> T=2048 tokens
#define HDIM 1024
#define IDIM 512
#define NEXP 16
#define TOPK 4
#define NTOK 2048
#define NSLOT (NTOK * TOPK)   // 8192 routed token-slots

// Workspace layout (bytes). Total ~21.3 MB (fits the demonstrated ws).
#define CNT_OFF   0                                   // int[16]
#define TOK_OFF   256                                 // int[NEXP*NTOK]  packed (t<<2)|k
#define WGT_OFF   (TOK_OFF + NEXP * NTOK * 4)         // float[NEXP*NTOK]
#define HS_OFF    (WGT_OFF + NEXP * NTOK * 4)         // float[NTOK*IDIM]
#define HR_OFF    (HS_OFF + NTOK * IDIM * 4)          // float[NSLOT*IDIM], row = (t<<2)|k

typedef __attribute__((ext_vector_type(8))) short s16x8;   // 8 bf16 = 4 VGPR (MFMA operand)
typedef __attribute__((ext_vector_type(4))) float f32x4;   // MFMA accumulator

// fp32 -> bf16 round-nearest-even (values are sane: no NaN/Inf handling needed)
__device__ inline unsigned short bf16_rne(float f) {
    unsigned int u = __float_as_uint(f);
    u += 0x7FFF + ((u >> 16) & 1);
    return (unsigned short)(u >> 16);
}
__device__ inline float bf16_up(unsigned short h) {
    return __uint_as_float(((unsigned int)h) << 16);
}

// ---------------------------------------------------------------------------
// Routing: scores = sigmoid(x @ gate_w^T), top-4, normalize, per-expert lists.
// ---------------------------------------------------------------------------
__global__ __launch_bounds__(64) void route_kernel(const float* __restrict__ x,
                                                   const float* __restrict__ gw,
                                                   int* __restrict__ cnt,
                                                   int* __restrict__ tok,
                                                   float* __restrict__ wgt) {
    const int t = blockIdx.x;
    const int lane = threadIdx.x;
    const float* xr = x + (size_t)t * HDIM;

    float acc[NEXP];
#pragma unroll
    for (int e = 0; e < NEXP; ++e) acc[e] = 0.f;

    for (int h = lane; h < HDIM; h += 64) {
        float xv = xr[h];
#pragma unroll
        for (int e = 0; e < NEXP; ++e) acc[e] += xv * gw[e * HDIM + h];
    }
#pragma unroll
    for (int e = 0; e < NEXP; ++e) {
        float v = acc[e];
#pragma unroll
        for (int off = 32; off > 0; off >>= 1) v += __shfl_xor(v, off, 64);
        acc[e] = v;
    }

    if (lane == 0) {
        float s[NEXP];
#pragma unroll
        for (int e = 0; e < NEXP; ++e) s[e] = 1.f / (1.f + expf(-acc[e]));
        bool used[NEXP];
#pragma unroll
        for (int e = 0; e < NEXP; ++e) used[e] = false;
        int id4[TOPK];
        float w4[TOPK];
        float sum = 0.f;
        for (int k = 0; k < TOPK; ++k) {
            float best = -1.f;
            int bi = 0;
            for (int e = 0; e < NEXP; ++e)
                if (!used[e] && s[e] > best) { best = s[e]; bi = e; }
            used[bi] = true;
            id4[k] = bi;
            w4[k] = best;
            sum += best;
        }
        float inv = 1.f / sum;
        for (int k = 0; k < TOPK; ++k) {
            int e = id4[k];
            int slot = atomicAdd(&cnt[e], 1);
            tok[e * NTOK + slot] = (t << 2) | k;
            wgt[e * NTOK + slot] = w4[k] * inv;
        }
    }
}

// ===========================================================================
// MFMA GEMM kernels. Tile 128x128x32, 256 threads (4 waves), wave-tile 64x64
// = 4x4 fragments of mfma_f32_16x16x32_bf16. fp32 inputs are split into
// bf16 hi+lo in LDS; product emulated with 3 MFMAs (hi*hi + hi*lo + lo*hi).
//
// LDS tile layout (A: [128 rows][32 k], B stored transposed [128 n][32 k]),
// bf16, 16B-chunk XOR swizzle: elem(row,k) at row*32 + ((k>>3 ^ (row&3))<<3)
// + (k&7). Fragment read (row r, k-group kg=lane>>4) = one ds_read_b128.
//
// Verified fragment maps (learn_hip m89/m91): A: row=lane&15, k=(lane>>4)*8+e;
// B: col=lane&15, k=(lane>>4)*8+e; D: col=lane&15, row=(lane>>4)*4+reg.
// ===========================================================================

// --------------------------- up: h = silu(A@W1) * (A@W2) -------------------
template<bool ROUTED>
__global__ __launch_bounds__(256) void up_kernel(const float* __restrict__ A,
                                                 const float* __restrict__ W1,
                                                 const float* __restrict__ W2,
                                                 const int* __restrict__ cnt,
                                                 const int* __restrict__ tok,
                                                 float* __restrict__ Hout) {
    int e = 0, nt = NTOK, m0, n0;
    if (ROUTED) {
        e = blockIdx.x;
        nt = cnt[e];
        m0 = blockIdx.y * 128;
        if (m0 >= nt) return;
        n0 = blockIdx.z * 128;
    } else {
        m0 = blockIdx.x * 128;
        n0 = blockIdx.y * 128;
    }

    __shared__ unsigned short Ahi[128 * 32], Alo[128 * 32];
    __shared__ unsigned short B1hi[128 * 32], B1lo[128 * 32];
    __shared__ unsigned short B2hi[128 * 32], B2lo[128 * 32];
    __shared__ int pk[128];

    const int tid = threadIdx.x;

    if (ROUTED) {
        for (int i = tid; i < 128; i += 256) {
            int s = m0 + i;
            pk[i] = (s < nt) ? tok[e * NTOK + s] : -1;
        }
        __syncthreads();
    }

    // A staging role: thread -> row am, k-half akh (16 floats each)
    const int am = tid >> 1;
    const int akh = (tid & 1) << 4;
    int arow;
    if (ROUTED) { int p = pk[am]; arow = (p >= 0) ? (p >> 2) : -1; }
    else arow = m0 + am;
    const float* aptr = (arow >= 0) ? (A + (size_t)arow * HDIM + akh) : (const float*)0;

    // B staging role: thread -> col bn, chunks {bc0, bc0+2}
    const int bn = tid & 127;
    const int bc0 = tid >> 7;
    const size_t eoffB = ROUTED ? (size_t)e * HDIM * IDIM : 0;
    const float* w1base = W1 + eoffB + n0 + bn;
    const float* w2base = W2 + eoffB + n0 + bn;

    const int lane = tid & 63, wid = tid >> 6;
    const int wr = wid >> 1, wc = wid & 1;
    const int lr = lane & 15, kg = lane >> 4;

    f32x4 accg[4][4], accu[4][4];
#pragma unroll
    for (int i = 0; i < 4; ++i)
#pragma unroll
        for (int j = 0; j < 4; ++j) {
            accg[i][j] = (f32x4){0.f, 0.f, 0.f, 0.f};
            accu[i][j] = (f32x4){0.f, 0.f, 0.f, 0.f};
        }

    for (int k0 = 0; k0 < HDIM; k0 += 32) {
        // ---- stage A (16 fp32 -> 2 chunks of bf16 hi/lo)
        {
            float v[16];
            if (arow >= 0) {
                const f32x4* p = (const f32x4*)(aptr + k0);
#pragma unroll
                for (int q = 0; q < 4; ++q) {
                    f32x4 t4 = p[q];
#pragma unroll
                    for (int j = 0; j < 4; ++j) v[q * 4 + j] = t4[j];
                }
            } else {
#pragma unroll
                for (int q = 0; q < 16; ++q) v[q] = 0.f;
            }
#pragma unroll
            for (int c = 0; c < 2; ++c) {
                s16x8 hi, lo;
#pragma unroll
                for (int j = 0; j < 8; ++j) {
                    float f = v[c * 8 + j];
                    unsigned short h = bf16_rne(f);
                    hi[j] = (short)h;
                    lo[j] = (short)bf16_rne(f - bf16_up(h));
                }
                int cc = (akh >> 3) + c;
                int off = am * 32 + ((cc ^ (am & 3)) << 3);
                *(s16x8*)&Ahi[off] = hi;
                *(s16x8*)&Alo[off] = lo;
            }
        }
        // ---- stage B1,B2 transposed: 8 k-rows per chunk, coalesced across wave
#pragma unroll
        for (int p = 0; p < 2; ++p) {
            int c = p * 2 + bc0;
            const float* r1 = w1base + (size_t)(k0 + c * 8) * IDIM;
            const float* r2 = w2base + (size_t)(k0 + c * 8) * IDIM;
            s16x8 h1, l1, h2, l2;
#pragma unroll
            for (int j = 0; j < 8; ++j) {
                float f1 = r1[j * IDIM];
                unsigned short a1 = bf16_rne(f1);
                h1[j] = (short)a1;
                l1[j] = (short)bf16_rne(f1 - bf16_up(a1));
                float f2 = r2[j * IDIM];
                unsigned short a2 = bf16_rne(f2);
                h2[j] = (short)a2;
                l2[j] = (short)bf16_rne(f2 - bf16_up(a2));
            }
            int off = bn * 32 + ((c ^ (bn & 3)) << 3);
            *(s16x8*)&B1hi[off] = h1;
            *(s16x8*)&B1lo[off] = l1;
            *(s16x8*)&B2hi[off] = h2;
            *(s16x8*)&B2lo[off] = l2;
        }
        __syncthreads();

        // ---- compute: 4x4 fragments x (3 split MFMAs) x 2 outputs
        s16x8 ah[4], al[4];
#pragma unroll
        for (int fm = 0; fm < 4; ++fm) {
            int r = wr * 64 + fm * 16 + lr;
            int off = r * 32 + ((kg ^ (r & 3)) << 3);
            ah[fm] = *(const s16x8*)&Ahi[off];
            al[fm] = *(const s16x8*)&Alo[off];
        }
#pragma unroll
        for (int fn = 0; fn < 4; ++fn) {
            int cix = wc * 64 + fn * 16 + lr;
            int off = cix * 32 + ((kg ^ (cix & 3)) << 3);
            s16x8 b1h = *(const s16x8*)&B1hi[off];
            s16x8 b1l = *(const s16x8*)&B1lo[off];
            s16x8 b2h = *(const s16x8*)&B2hi[off];
            s16x8 b2l = *(const s16x8*)&B2lo[off];
#pragma unroll
            for (int fm = 0; fm < 4; ++fm) {
                accg[fm][fn] = __builtin_amdgcn_mfma_f32_16x16x32_bf16(ah[fm], b1h, accg[fm][fn], 0, 0, 0);
                accg[fm][fn] = __builtin_amdgcn_mfma_f32_16x16x32_bf16(ah[fm], b1l, accg[fm][fn], 0, 0, 0);
                accg[fm][fn] = __builtin_amdgcn_mfma_f32_16x16x32_bf16(al[fm], b1h, accg[fm][fn], 0, 0, 0);
                accu[fm][fn] = __builtin_amdgcn_mfma_f32_16x16x32_bf16(ah[fm], b2h, accu[fm][fn], 0, 0, 0);
                accu[fm][fn] = __builtin_amdgcn_mfma_f32_16x16x32_bf16(ah[fm], b2l, accu[fm][fn], 0, 0, 0);
                accu[fm][fn] = __builtin_amdgcn_mfma_f32_16x16x32_bf16(al[fm], b2h, accu[fm][fn], 0, 0, 0);
            }
        }
        __syncthreads();
    }

    // ---- epilogue: h = silu(g) * u
#pragma unroll
    for (int fm = 0; fm < 4; ++fm) {
        int mbase = wr * 64 + fm * 16 + kg * 4;
#pragma unroll
        for (int r = 0; r < 4; ++r) {
            int m = mbase + r;
            int orow;
            if (ROUTED) {
                int p = pk[m];
                if (p < 0) continue;
                orow = p;
            } else {
                orow = m0 + m;
            }
#pragma unroll
            for (int fn = 0; fn < 4; ++fn) {
                float g = accg[fm][fn][r], u = accu[fm][fn][r];
                float sil = g / (1.f + expf(-g));
                Hout[(size_t)orow * IDIM + n0 + wc * 64 + fn * 16 + lr] = sil * u;
            }
        }
    }
}

// --------------------------- down: out = H @ Wd ----------------------------
template<bool ROUTED>
__global__ __launch_bounds__(256) void down_kernel(const float* __restrict__ Hin,
                                                   const float* __restrict__ Wdn,
                                                   const int* __restrict__ cnt,
                                                   const int* __restrict__ tok,
                                                   const float* __restrict__ wgt,
                                                   float* __restrict__ out) {
    int e = 0, nt = NTOK, m0, n0;
    if (ROUTED) {
        e = blockIdx.x;
        nt = cnt[e];
        m0 = blockIdx.y * 128;
        if (m0 >= nt) return;
        n0 = blockIdx.z * 128;
    } else {
        m0 = blockIdx.x * 128;
        n0 = blockIdx.y * 128;
    }

    __shared__ unsigned short Ahi[128 * 32], Alo[128 * 32];
    __shared__ unsigned short Bhi[128 * 32], Blo[128 * 32];
    __shared__ int pk[128];
    __shared__ float wts[128];

    const int tid = threadIdx.x;

    if (ROUTED) {
        for (int i = tid; i < 128; i += 256) {
            int s = m0 + i;
            pk[i] = (s < nt) ? tok[e * NTOK + s] : -1;
            wts[i] = (s < nt) ? wgt[e * NTOK + s] : 0.f;
        }
        __syncthreads();
    }

    const int am = tid >> 1;
    const int akh = (tid & 1) << 4;
    int arow;
    if (ROUTED) { arow = pk[am]; }   // hr is indexed by the packed slot id
    else arow = m0 + am;
    const float* aptr = (arow >= 0) ? (Hin + (size_t)arow * IDIM + akh) : (const float*)0;

    const int bn = tid & 127;
    const int bc0 = tid >> 7;
    const size_t eoffB = ROUTED ? (size_t)e * IDIM * HDIM : 0;
    const float* wbase = Wdn + eoffB + n0 + bn;

    const int lane = tid & 63, wid = tid >> 6;
    const int wr = wid >> 1, wc = wid & 1;
    const int lr = lane & 15, kg = lane >> 4;

    f32x4 acc[4][4];
#pragma unroll
    for (int i = 0; i < 4; ++i)
#pragma unroll
        for (int j = 0; j < 4; ++j) acc[i][j] = (f32x4){0.f, 0.f, 0.f, 0.f};

    for (int k0 = 0; k0 < IDIM; k0 += 32) {
        {
            float v[16];
            if (arow >= 0) {
                const f32x4* p = (const f32x4*)(aptr + k0);
#pragma unroll
                for (int q = 0; q < 4; ++q) {
                    f32x4 t4 = p[q];
#pragma unroll
                    for (int j = 0; j < 4; ++j) v[q * 4 + j] = t4[j];
                }
            } else {
#pragma unroll
                for (int q = 0; q < 16; ++q) v[q] = 0.f;
            }
#pragma unroll
            for (int c = 0; c < 2; ++c) {
                s16x8 hi, lo;
#pragma unroll
                for (int j = 0; j < 8; ++j) {
                    float f = v[c * 8 + j];
                    unsigned short h = bf16_rne(f);
                    hi[j] = (short)h;
                    lo[j] = (short)bf16_rne(f - bf16_up(h));
                }
                int cc = (akh >> 3) + c;
                int off = am * 32 + ((cc ^ (am & 3)) << 3);
                *(s16x8*)&Ahi[off] = hi;
                *(s16x8*)&Alo[off] = lo;
            }
        }
#pragma unroll
        for (int p = 0; p < 2; ++p) {
            int c = p * 2 + bc0;
            const float* r1 = wbase + (size_t)(k0 + c * 8) * HDIM;
            s16x8 h1, l1;
#pragma unroll
            for (int j = 0; j < 8; ++j) {
                float f1 = r1[j * HDIM];
                unsigned short a1 = bf16_rne(f1);
                h1[j] = (short)a1;
                l1[j] = (short)bf16_rne(f1 - bf16_up(a1));
            }
            int off = bn * 32 + ((c ^ (bn & 3)) << 3);
            *(s16x8*)&Bhi[off] = h1;
            *(s16x8*)&Blo[off] = l1;
        }
        __syncthreads();

        s16x8 ah[4], al[4];
#pragma unroll
        for (int fm = 0; fm < 4; ++fm) {
            int r = wr * 64 + fm * 16 + lr;
            int off = r * 32 + ((kg ^ (r & 3)) << 3);
            ah[fm] = *(const s16x8*)&Ahi[off];
            al[fm] = *(const s16x8*)&Alo[off];
        }
#pragma unroll
        for (int fn = 0; fn < 4; ++fn) {
            int cix = wc * 64 + fn * 16 + lr;
            int off = cix * 32 + ((kg ^ (cix & 3)) << 3);
            s16x8 bh = *(const s16x8*)&Bhi[off];
            s16x8 bl = *(const s16x8*)&Blo[off];
#pragma unroll
            for (int fm = 0; fm < 4; ++fm) {
                acc[fm][fn] = __builtin_amdgcn_mfma_f32_16x16x32_bf16(ah[fm], bh, acc[fm][fn], 0, 0, 0);
                acc[fm][fn] = __builtin_amdgcn_mfma_f32_16x16x32_bf16(ah[fm], bl, acc[fm][fn], 0, 0, 0);
                acc[fm][fn] = __builtin_amdgcn_mfma_f32_16x16x32_bf16(al[fm], bh, acc[fm][fn], 0, 0, 0);
            }
        }
        __syncthreads();
    }

#pragma unroll
    for (int fm = 0; fm < 4; ++fm) {
        int mbase = wr * 64 + fm * 16 + kg * 4;
#pragma unroll
        for (int r = 0; r < 4; ++r) {
            int m = mbase + r;
#pragma unroll
            for (int fn = 0; fn < 4; ++fn) {
                int col = n0 + wc * 64 + fn * 16 + lr;
                if (ROUTED) {
                    int p = pk[m];
                    if (p < 0) continue;
                    atomicAdd(&out[(size_t)(p >> 2) * HDIM + col], wts[m] * acc[fm][fn][r]);
                } else {
                    out[(size_t)(m0 + m) * HDIM + col] = acc[fm][fn][r];
                }
            }
        }
    }
}

// ---------------------------------------------------------------------------
extern "C" void kernel_launch(void* const* d_in, const int* in_sizes, int n_in,
                              void* d_out, int out_size, void* d_ws, size_t ws_size,
                              hipStream_t stream) {
    const float* x  = (const float*)d_in[0];   // [T,H]
    const float* gw = (const float*)d_in[1];   // [E,H]
    const float* Wg = (const float*)d_in[2];   // [E,H,I]
    const float* Wu = (const float*)d_in[3];   // [E,H,I]
    const float* Wd = (const float*)d_in[4];   // [E,I,H]
    const float* sg = (const float*)d_in[5];   // [H,I]
    const float* su = (const float*)d_in[6];   // [H,I]
    const float* sd = (const float*)d_in[7];   // [I,H]
    float* out = (float*)d_out;

    char* ws = (char*)d_ws;
    int* cnt   = (int*)(ws + CNT_OFF);
    int* tok   = (int*)(ws + TOK_OFF);
    float* wgt = (float*)(ws + WGT_OFF);
    float* hs  = (float*)(ws + HS_OFF);
    float* hr  = (float*)(ws + HR_OFF);

    hipMemsetAsync(cnt, 0, NEXP * sizeof(int), stream);

    route_kernel<<<NTOK, 64, 0, stream>>>(x, gw, cnt, tok, wgt);
    // shared expert
    up_kernel<false><<<dim3(NTOK / 128, IDIM / 128), 256, 0, stream>>>(x, sg, su, cnt, tok, hs);
    down_kernel<false><<<dim3(NTOK / 128, HDIM / 128), 256, 0, stream>>>(hs, sd, cnt, tok, wgt, out);
    // routed experts (dead blocks past cnt[e] exit immediately)
    up_kernel<true><<<dim3(NEXP, NTOK / 128, IDIM / 128), 256, 0, stream>>>(x, Wg, Wu, cnt, tok, hr);
    down_kernel<true><<<dim3(NEXP, NTOK / 128, HDIM / 128), 256, 0, stream>>>(hr, Wd, cnt, tok, wgt, out);
}

// Round 5
// 537.343 us; speedup vs baseline: 1.7796x; 1.7796x over previous
//
#include <hip/hip_runtime.h>
#include <math.h>

// Problem constants: B=2, S=1024 -> T=2048 tokens
#define HDIM 1024
#define IDIM 512
#define NEXP 16
#define TOPK 4
#define NTOK 2048
#define NSLOT (NTOK * TOPK)      // 8192 routed slots
#define HROWS (NSLOT + NTOK)     // + 2048 shared rows = 10240

typedef __attribute__((ext_vector_type(8))) short s16x8;   // 8 bf16 (MFMA operand)
typedef __attribute__((ext_vector_type(4))) float f32x4;
typedef __attribute__((ext_vector_type(4))) unsigned short u16x4;

__device__ inline unsigned short bf16_rne(float f) {
    unsigned int u = __float_as_uint(f);
    u += 0x7FFF + ((u >> 16) & 1);
    return (unsigned short)(u >> 16);
}
__device__ inline float bf16_up(unsigned short h) {
    return __uint_as_float(((unsigned int)h) << 16);
}
// LDS chunk swizzle: read/write position = kg ^ SWZ4(n). Involution; gives
// <=2-way bank aliasing on ds_read_b128 across 16 consecutive n-rows.
__device__ inline int swz4(int n) { return (n & 3) ^ ((n >> 2) & 3); }

// async global->LDS, 16B per lane (dest = wave-uniform base + lane*16)
typedef __attribute__((address_space(3))) unsigned int lds_uint_t;
typedef __attribute__((address_space(1))) unsigned int glob_uint_t;
#define GLD16(gsrc, ldst) __builtin_amdgcn_global_load_lds( \
    (const glob_uint_t*)(gsrc), (lds_uint_t*)(ldst), 16, 0, 0)

// ===========================================================================
// FAST-PATH workspace layout (bf16 hi/lo planes, 17 "experts": 16 routed +
// shared). Total ~130.3 MiB; gated on ws_size at launch.
// ===========================================================================
#define PLANE_W  ((size_t)17 * 512 * 1024)        // elems per weight plane
#define O_CNT    ((size_t)0)                      // int[17] (memset 128B)
#define O_TOK    ((size_t)256)                    // int[17*2048]
#define O_WGT    (O_TOK + (size_t)17 * NTOK * 4)
#define O_XH     (O_WGT + (size_t)17 * NTOK * 4)  // ushort[2048*1024]
#define O_XL     (O_XH + (size_t)NTOK * HDIM * 2)
#define O_WG_H   (O_XL + (size_t)NTOK * HDIM * 2)
#define O_WG_L   (O_WG_H + PLANE_W * 2)
#define O_WU_H   (O_WG_L + PLANE_W * 2)
#define O_WU_L   (O_WU_H + PLANE_W * 2)
#define O_WD_H   (O_WU_L + PLANE_W * 2)
#define O_WD_L   (O_WD_H + PLANE_W * 2)
#define O_HH     (O_WD_L + PLANE_W * 2)           // ushort[10240*512]
#define O_HL     (O_HH + (size_t)HROWS * IDIM * 2)
#define FAST_NEED (O_HL + (size_t)HROWS * IDIM * 2)

// ===========================================================================
// Routing (both paths): sigmoid(x@gw^T), top-4, normalize, per-expert lists.
// ===========================================================================
__global__ __launch_bounds__(64) void route_kernel(const float* __restrict__ x,
                                                   const float* __restrict__ gw,
                                                   int* __restrict__ cnt,
                                                   int* __restrict__ tok,
                                                   float* __restrict__ wgt) {
    const int t = blockIdx.x;
    const int lane = threadIdx.x;
    const float* xr = x + (size_t)t * HDIM;

    float acc[NEXP];
#pragma unroll
    for (int e = 0; e < NEXP; ++e) acc[e] = 0.f;
    for (int h = lane; h < HDIM; h += 64) {
        float xv = xr[h];
#pragma unroll
        for (int e = 0; e < NEXP; ++e) acc[e] += xv * gw[e * HDIM + h];
    }
#pragma unroll
    for (int e = 0; e < NEXP; ++e) {
        float v = acc[e];
#pragma unroll
        for (int off = 32; off > 0; off >>= 1) v += __shfl_xor(v, off, 64);
        acc[e] = v;
    }
    if (lane == 0) {
        float s[NEXP];
#pragma unroll
        for (int e = 0; e < NEXP; ++e) s[e] = 1.f / (1.f + expf(-acc[e]));
        bool used[NEXP];
#pragma unroll
        for (int e = 0; e < NEXP; ++e) used[e] = false;
        int id4[TOPK]; float w4[TOPK]; float sum = 0.f;
        for (int k = 0; k < TOPK; ++k) {
            float best = -1.f; int bi = 0;
            for (int e = 0; e < NEXP; ++e)
                if (!used[e] && s[e] > best) { best = s[e]; bi = e; }
            used[bi] = true; id4[k] = bi; w4[k] = best; sum += best;
        }
        float inv = 1.f / sum;
        for (int k = 0; k < TOPK; ++k) {
            int e = id4[k];
            int slot = atomicAdd(&cnt[e], 1);
            tok[e * NTOK + slot] = (t << 2) | k;
            wgt[e * NTOK + slot] = w4[k] * inv;
        }
    }
}

// ===========================================================================
// FAST PATH
// ===========================================================================

// ---- x -> bf16 hi/lo planes; also init shared-expert routing (expert 16) ---
__global__ __launch_bounds__(256) void conv_act(const float* __restrict__ x,
                                                unsigned short* __restrict__ xh,
                                                unsigned short* __restrict__ xl,
                                                int* __restrict__ cnt,
                                                int* __restrict__ tok,
                                                float* __restrict__ wgt) {
    const int t = blockIdx.x;
    const int tid = threadIdx.x;
    if (tid == 0) {
        tok[16 * NTOK + t] = (t << 2);
        wgt[16 * NTOK + t] = 1.0f;
        if (t == 0) cnt[16] = NTOK;
    }
    const float* src = x + (size_t)t * HDIM;
    unsigned short* dh = xh + (size_t)t * HDIM;
    unsigned short* dl = xl + (size_t)t * HDIM;
    int i = tid * 4;
    f32x4 v = *(const f32x4*)(src + i);
    u16x4 hv, lv;
#pragma unroll
    for (int j = 0; j < 4; ++j) {
        unsigned short h = bf16_rne(v[j]);
        hv[j] = h;
        lv[j] = bf16_rne(v[j] - bf16_up(h));
    }
    *(u16x4*)(dh + i) = hv;
    *(u16x4*)(dl + i) = lv;
}

// ---- weight [K][N] -> transposed, swizzled bf16 hi/lo planes [n][k] --------
// grid (K/64, N/128, 17); z==16 selects the shared-expert weight.
__global__ __launch_bounds__(256) void conv_w(const float* __restrict__ Wm,
                                              const float* __restrict__ Ws,
                                              unsigned short* __restrict__ dh,
                                              unsigned short* __restrict__ dl,
                                              int K, int N) {
    __shared__ float tile[64][129];
    const int k0 = blockIdx.x * 64, n0 = blockIdx.y * 128, z = blockIdx.z;
    const float* src = (z < 16) ? (Wm + (size_t)z * K * N) : Ws;
    const size_t dbase = (size_t)z * 512 * 1024;   // N*K identical for all mats
    const int tid = threadIdx.x;

#pragma unroll
    for (int i = 0; i < 8; ++i) {                  // 2048 vec4 loads, coalesced
        int v = tid + i * 256;
        int k = v >> 5, nv = v & 31;
        f32x4 t4 = *(const f32x4*)(src + (size_t)(k0 + k) * N + n0 + nv * 4);
#pragma unroll
        for (int j = 0; j < 4; ++j) tile[k][nv * 4 + j] = t4[j];
    }
    __syncthreads();
#pragma unroll
    for (int i = 0; i < 4; ++i) {                  // 1024 output chunks of 8
        int c = tid + i * 256;
        int n = c >> 3, dc = c & 7;
        int tl = dc >> 2, kg = dc & 3;
        int ng = n0 + n;
        s16x8 hv, lv;
#pragma unroll
        for (int j = 0; j < 8; ++j) {
            float f = tile[tl * 32 + kg * 8 + j][n];
            unsigned short h = bf16_rne(f);
            hv[j] = (short)h;
            lv[j] = (short)bf16_rne(f - bf16_up(h));
        }
        size_t off = dbase + (size_t)ng * K + k0 + tl * 32 + ((kg ^ swz4(ng)) << 3);
        *(s16x8*)(dh + off) = hv;
        *(s16x8*)(dl + off) = lv;
    }
}

// ---- grouped GEMM: tile 128m x 64n, BK=32, 4 waves (2x2), wave 64x32 -------
// UP:  A = xc (token rows), B = {Wg,Wu} planes; out = h planes (silu(g)*u).
// DOWN:A = hc (slot rows),  B = Wd planes; out += wgt * acc (atomic).
// B double-buffered in LDS via global_load_lds; A direct global->reg.
template<bool UP>
__global__ __launch_bounds__(256, 2) void moe_gemm(
        const unsigned short* __restrict__ Ah, const unsigned short* __restrict__ Al,
        const unsigned short* __restrict__ B1h, const unsigned short* __restrict__ B1l,
        const unsigned short* __restrict__ B2h, const unsigned short* __restrict__ B2l,
        const int* __restrict__ cnt, const int* __restrict__ tok,
        const float* __restrict__ wgt,
        unsigned short* __restrict__ Hh, unsigned short* __restrict__ Hl,
        float* __restrict__ out) {
    constexpr int KD = UP ? HDIM : IDIM;
    constexpr int NT = KD / 32;
    constexpr int NP = UP ? 4 : 2;                 // staged planes

    const int e = blockIdx.x;
    const int nt = cnt[e];
    const int m0 = blockIdx.y * 128;
    if (m0 >= nt) return;
    const int n0 = blockIdx.z * 64;

    __shared__ unsigned short Bb[2][NP][64 * 32];
    __shared__ int pk[128];
    __shared__ float wts[128];

    const int tid = threadIdx.x;
    for (int i = tid; i < 128; i += 256) {
        int s = m0 + i;
        pk[i] = (s < nt) ? tok[e * NTOK + s] : -1;
        wts[i] = (s < nt) ? wgt[e * NTOK + s] : 0.f;
    }
    __syncthreads();

    const int lane = tid & 63, wid = tid >> 6;
    const int wr = wid >> 1, wc = wid & 1;
    const int lr = lane & 15, kg = lane >> 4;

    // ---- A fragment row pointers (direct global, per-lane gather)
    const unsigned short* pAh[4];
    const unsigned short* pAl[4];
#pragma unroll
    for (int fm = 0; fm < 4; ++fm) {
        int m = wr * 64 + fm * 16 + lr;
        int p = pk[m];
        size_t row;
        if (UP) row = (p >= 0) ? (size_t)(p >> 2) : 0;
        else    row = (p < 0) ? 0 : (size_t)((e == 16) ? (NSLOT + (p >> 2)) : p);
        pAh[fm] = Ah + row * KD;
        pAl[fm] = Al + row * KD;
    }

    // ---- B staging source (pre-transposed, pre-swizzled planes)
    const size_t eoff = (size_t)e * 512 * 1024;
    const unsigned short* bp[4];
    bp[0] = B1h + eoff;
    bp[1] = B1l + eoff;
    if (UP) { bp[2] = B2h + eoff; bp[3] = B2l + eoff; }
    const size_t soff = (size_t)(n0 + (tid >> 2)) * KD + ((tid & 3) << 3);

    f32x4 acc1[4][2], acc2[4][2];
#pragma unroll
    for (int i = 0; i < 4; ++i)
#pragma unroll
        for (int j = 0; j < 2; ++j) {
            acc1[i][j] = (f32x4){0.f, 0.f, 0.f, 0.f};
            if (UP) acc2[i][j] = (f32x4){0.f, 0.f, 0.f, 0.f};
        }

#define STAGE(buf, k0)                                            \
    {                                                             \
        _Pragma("unroll")                                         \
        for (int pl = 0; pl < NP; ++pl)                           \
            GLD16(bp[pl] + soff + (k0), &Bb[buf][pl][tid << 3]);  \
    }

#define COMPUTE(buf, k0)                                                          \
    {                                                                             \
        s16x8 ah[4], al[4];                                                       \
        _Pragma("unroll")                                                         \
        for (int fm = 0; fm < 4; ++fm) {                                          \
            ah[fm] = *(const s16x8*)(pAh[fm] + (k0) + (kg << 3));                 \
            al[fm] = *(const s16x8*)(pAl[fm] + (k0) + (kg << 3));                 \
        }                                                                         \
        _Pragma("unroll")                                                         \
        for (int fn = 0; fn < 2; ++fn) {                                          \
            int nl = wc * 32 + fn * 16 + lr;                                      \
            int off = (nl << 5) + ((kg ^ swz4(nl)) << 3);                         \
            s16x8 b1h = *(const s16x8*)&Bb[buf][0][off];                          \
            s16x8 b1l = *(const s16x8*)&Bb[buf][1][off];                          \
            _Pragma("unroll")                                                     \
            for (int fm = 0; fm < 4; ++fm) {                                      \
                acc1[fm][fn] = __builtin_amdgcn_mfma_f32_16x16x32_bf16(           \
                    ah[fm], b1h, acc1[fm][fn], 0, 0, 0);                          \
                acc1[fm][fn] = __builtin_amdgcn_mfma_f32_16x16x32_bf16(           \
                    ah[fm], b1l, acc1[fm][fn], 0, 0, 0);                          \
                acc1[fm][fn] = __builtin_amdgcn_mfma_f32_16x16x32_bf16(           \
                    al[fm], b1h, acc1[fm][fn], 0, 0, 0);                          \
            }                                                                     \
            if (UP) {                                                             \
                s16x8 b2h = *(const s16x8*)&Bb[buf][NP - 2][off];                 \
                s16x8 b2l = *(const s16x8*)&Bb[buf][NP - 1][off];                 \
                _Pragma("unroll")                                                 \
                for (int fm = 0; fm < 4; ++fm) {                                  \
                    acc2[fm][fn] = __builtin_amdgcn_mfma_f32_16x16x32_bf16(       \
                        ah[fm], b2h, acc2[fm][fn], 0, 0, 0);                      \
                    acc2[fm][fn] = __builtin_amdgcn_mfma_f32_16x16x32_bf16(       \
                        ah[fm], b2l, acc2[fm][fn], 0, 0, 0);                      \
                    acc2[fm][fn] = __builtin_amdgcn_mfma_f32_16x16x32_bf16(       \
                        al[fm], b2h, acc2[fm][fn], 0, 0, 0);                      \
                }                                                                 \
            }                                                                     \
        }                                                                         \
    }

    // 2-phase double-buffered K-loop (stage t+1 in flight while computing t;
    // __syncthreads drains vmcnt/lgkmcnt before any wave touches the buffer).
    STAGE(0, 0);
    __syncthreads();
    int cur = 0;
    for (int t = 0; t < NT - 1; ++t) {
        STAGE(cur ^ 1, (t + 1) * 32);
        COMPUTE(cur, t * 32);
        __syncthreads();
        cur ^= 1;
    }
    COMPUTE(cur, (NT - 1) * 32);

#undef STAGE
#undef COMPUTE

    // ---- epilogue
#pragma unroll
    for (int fm = 0; fm < 4; ++fm) {
#pragma unroll
        for (int r = 0; r < 4; ++r) {
            int m = wr * 64 + fm * 16 + kg * 4 + r;
            int p = pk[m];
            if (p < 0) continue;
            if (UP) {
                size_t hrow = (e == 16) ? (size_t)(NSLOT + (p >> 2)) : (size_t)p;
#pragma unroll
                for (int fn = 0; fn < 2; ++fn) {
                    int col = n0 + wc * 32 + fn * 16 + lr;
                    float g = acc1[fm][fn][r], u = acc2[fm][fn][r];
                    float v = (g / (1.f + expf(-g))) * u;
                    unsigned short h = bf16_rne(v);
                    Hh[hrow * IDIM + col] = h;
                    Hl[hrow * IDIM + col] = bf16_rne(v - bf16_up(h));
                }
            } else {
                int tkn = p >> 2;
                float w = wts[m];
#pragma unroll
                for (int fn = 0; fn < 2; ++fn) {
                    int col = n0 + wc * 32 + fn * 16 + lr;
                    atomicAdd(&out[(size_t)tkn * HDIM + col], w * acc1[fm][fn][r]);
                }
            }
        }
    }
}

// ===========================================================================
// FALLBACK PATH (round-4 kernels, verified passing): used if ws too small.
// ===========================================================================
#define FB_CNT_OFF   0
#define FB_TOK_OFF   256
#define FB_WGT_OFF   (FB_TOK_OFF + NEXP * NTOK * 4)
#define FB_HS_OFF    (FB_WGT_OFF + NEXP * NTOK * 4)
#define FB_HR_OFF    (FB_HS_OFF + NTOK * IDIM * 4)

template<bool ROUTED>
__global__ __launch_bounds__(256) void fb_up(const float* __restrict__ A,
                                             const float* __restrict__ W1,
                                             const float* __restrict__ W2,
                                             const int* __restrict__ cnt,
                                             const int* __restrict__ tok,
                                             float* __restrict__ Hout) {
    int e = 0, nt = NTOK, m0, n0;
    if (ROUTED) {
        e = blockIdx.x; nt = cnt[e]; m0 = blockIdx.y * 128;
        if (m0 >= nt) return;
        n0 = blockIdx.z * 128;
    } else { m0 = blockIdx.x * 128; n0 = blockIdx.y * 128; }

    __shared__ unsigned short Ahi[128 * 32], Alo[128 * 32];
    __shared__ unsigned short B1hi[128 * 32], B1lo[128 * 32];
    __shared__ unsigned short B2hi[128 * 32], B2lo[128 * 32];
    __shared__ int pk[128];
    const int tid = threadIdx.x;
    if (ROUTED) {
        for (int i = tid; i < 128; i += 256) {
            int s = m0 + i;
            pk[i] = (s < nt) ? tok[e * NTOK + s] : -1;
        }
        __syncthreads();
    }
    const int am = tid >> 1;
    const int akh = (tid & 1) << 4;
    int arow;
    if (ROUTED) { int p = pk[am]; arow = (p >= 0) ? (p >> 2) : -1; }
    else arow = m0 + am;
    const float* aptr = (arow >= 0) ? (A + (size_t)arow * HDIM + akh) : (const float*)0;
    const int bn = tid & 127;
    const int bc0 = tid >> 7;
    const size_t eoffB = ROUTED ? (size_t)e * HDIM * IDIM : 0;
    const float* w1base = W1 + eoffB + n0 + bn;
    const float* w2base = W2 + eoffB + n0 + bn;
    const int lane = tid & 63, wid = tid >> 6;
    const int wr = wid >> 1, wc = wid & 1;
    const int lr = lane & 15, kg = lane >> 4;
    f32x4 accg[4][4], accu[4][4];
#pragma unroll
    for (int i = 0; i < 4; ++i)
#pragma unroll
        for (int j = 0; j < 4; ++j) {
            accg[i][j] = (f32x4){0.f, 0.f, 0.f, 0.f};
            accu[i][j] = (f32x4){0.f, 0.f, 0.f, 0.f};
        }
    for (int k0 = 0; k0 < HDIM; k0 += 32) {
        {
            float v[16];
            if (arow >= 0) {
                const f32x4* p = (const f32x4*)(aptr + k0);
#pragma unroll
                for (int q = 0; q < 4; ++q) { f32x4 t4 = p[q];
#pragma unroll
                    for (int j = 0; j < 4; ++j) v[q * 4 + j] = t4[j]; }
            } else {
#pragma unroll
                for (int q = 0; q < 16; ++q) v[q] = 0.f;
            }
#pragma unroll
            for (int c = 0; c < 2; ++c) {
                s16x8 hi, lo;
#pragma unroll
                for (int j = 0; j < 8; ++j) {
                    float f = v[c * 8 + j];
                    unsigned short h = bf16_rne(f);
                    hi[j] = (short)h;
                    lo[j] = (short)bf16_rne(f - bf16_up(h));
                }
                int cc = (akh >> 3) + c;
                int off = am * 32 + ((cc ^ (am & 3)) << 3);
                *(s16x8*)&Ahi[off] = hi;
                *(s16x8*)&Alo[off] = lo;
            }
        }
#pragma unroll
        for (int p = 0; p < 2; ++p) {
            int c = p * 2 + bc0;
            const float* r1 = w1base + (size_t)(k0 + c * 8) * IDIM;
            const float* r2 = w2base + (size_t)(k0 + c * 8) * IDIM;
            s16x8 h1, l1, h2, l2;
#pragma unroll
            for (int j = 0; j < 8; ++j) {
                float f1 = r1[j * IDIM];
                unsigned short a1 = bf16_rne(f1);
                h1[j] = (short)a1;
                l1[j] = (short)bf16_rne(f1 - bf16_up(a1));
                float f2 = r2[j * IDIM];
                unsigned short a2 = bf16_rne(f2);
                h2[j] = (short)a2;
                l2[j] = (short)bf16_rne(f2 - bf16_up(a2));
            }
            int off = bn * 32 + ((c ^ (bn & 3)) << 3);
            *(s16x8*)&B1hi[off] = h1;
            *(s16x8*)&B1lo[off] = l1;
            *(s16x8*)&B2hi[off] = h2;
            *(s16x8*)&B2lo[off] = l2;
        }
        __syncthreads();
        s16x8 ah[4], al[4];
#pragma unroll
        for (int fm = 0; fm < 4; ++fm) {
            int r = wr * 64 + fm * 16 + lr;
            int off = r * 32 + ((kg ^ (r & 3)) << 3);
            ah[fm] = *(const s16x8*)&Ahi[off];
            al[fm] = *(const s16x8*)&Alo[off];
        }
#pragma unroll
        for (int fn = 0; fn < 4; ++fn) {
            int cix = wc * 64 + fn * 16 + lr;
            int off = cix * 32 + ((kg ^ (cix & 3)) << 3);
            s16x8 b1h = *(const s16x8*)&B1hi[off];
            s16x8 b1l = *(const s16x8*)&B1lo[off];
            s16x8 b2h = *(const s16x8*)&B2hi[off];
            s16x8 b2l = *(const s16x8*)&B2lo[off];
#pragma unroll
            for (int fm = 0; fm < 4; ++fm) {
                accg[fm][fn] = __builtin_amdgcn_mfma_f32_16x16x32_bf16(ah[fm], b1h, accg[fm][fn], 0, 0, 0);
                accg[fm][fn] = __builtin_amdgcn_mfma_f32_16x16x32_bf16(ah[fm], b1l, accg[fm][fn], 0, 0, 0);
                accg[fm][fn] = __builtin_amdgcn_mfma_f32_16x16x32_bf16(al[fm], b1h, accg[fm][fn], 0, 0, 0);
                accu[fm][fn] = __builtin_amdgcn_mfma_f32_16x16x32_bf16(ah[fm], b2h, accu[fm][fn], 0, 0, 0);
                accu[fm][fn] = __builtin_amdgcn_mfma_f32_16x16x32_bf16(ah[fm], b2l, accu[fm][fn], 0, 0, 0);
                accu[fm][fn] = __builtin_amdgcn_mfma_f32_16x16x32_bf16(al[fm], b2h, accu[fm][fn], 0, 0, 0);
            }
        }
        __syncthreads();
    }
#pragma unroll
    for (int fm = 0; fm < 4; ++fm) {
        int mbase = wr * 64 + fm * 16 + kg * 4;
#pragma unroll
        for (int r = 0; r < 4; ++r) {
            int m = mbase + r;
            int orow;
            if (ROUTED) { int p = pk[m]; if (p < 0) continue; orow = p; }
            else orow = m0 + m;
#pragma unroll
            for (int fn = 0; fn < 4; ++fn) {
                float g = accg[fm][fn][r], u = accu[fm][fn][r];
                float sil = g / (1.f + expf(-g));
                Hout[(size_t)orow * IDIM + n0 + wc * 64 + fn * 16 + lr] = sil * u;
            }
        }
    }
}

template<bool ROUTED>
__global__ __launch_bounds__(256) void fb_down(const float* __restrict__ Hin,
                                               const float* __restrict__ Wdn,
                                               const int* __restrict__ cnt,
                                               const int* __restrict__ tok,
                                               const float* __restrict__ wgt,
                                               float* __restrict__ out) {
    int e = 0, nt = NTOK, m0, n0;
    if (ROUTED) {
        e = blockIdx.x; nt = cnt[e]; m0 = blockIdx.y * 128;
        if (m0 >= nt) return;
        n0 = blockIdx.z * 128;
    } else { m0 = blockIdx.x * 128; n0 = blockIdx.y * 128; }

    __shared__ unsigned short Ahi[128 * 32], Alo[128 * 32];
    __shared__ unsigned short Bhi[128 * 32], Blo[128 * 32];
    __shared__ int pk[128];
    __shared__ float wts[128];
    const int tid = threadIdx.x;
    if (ROUTED) {
        for (int i = tid; i < 128; i += 256) {
            int s = m0 + i;
            pk[i] = (s < nt) ? tok[e * NTOK + s] : -1;
            wts[i] = (s < nt) ? wgt[e * NTOK + s] : 0.f;
        }
        __syncthreads();
    }
    const int am = tid >> 1;
    const int akh = (tid & 1) << 4;
    int arow;
    if (ROUTED) arow = pk[am];
    else arow = m0 + am;
    const float* aptr = (arow >= 0) ? (Hin + (size_t)arow * IDIM + akh) : (const float*)0;
    const int bn = tid & 127;
    const int bc0 = tid >> 7;
    const size_t eoffB = ROUTED ? (size_t)e * IDIM * HDIM : 0;
    const float* wbase = Wdn + eoffB + n0 + bn;
    const int lane = tid & 63, wid = tid >> 6;
    const int wr = wid >> 1, wc = wid & 1;
    const int lr = lane & 15, kg = lane >> 4;
    f32x4 acc[4][4];
#pragma unroll
    for (int i = 0; i < 4; ++i)
#pragma unroll
        for (int j = 0; j < 4; ++j) acc[i][j] = (f32x4){0.f, 0.f, 0.f, 0.f};
    for (int k0 = 0; k0 < IDIM; k0 += 32) {
        {
            float v[16];
            if (arow >= 0) {
                const f32x4* p = (const f32x4*)(aptr + k0);
#pragma unroll
                for (int q = 0; q < 4; ++q) { f32x4 t4 = p[q];
#pragma unroll
                    for (int j = 0; j < 4; ++j) v[q * 4 + j] = t4[j]; }
            } else {
#pragma unroll
                for (int q = 0; q < 16; ++q) v[q] = 0.f;
            }
#pragma unroll
            for (int c = 0; c < 2; ++c) {
                s16x8 hi, lo;
#pragma unroll
                for (int j = 0; j < 8; ++j) {
                    float f = v[c * 8 + j];
                    unsigned short h = bf16_rne(f);
                    hi[j] = (short)h;
                    lo[j] = (short)bf16_rne(f - bf16_up(h));
                }
                int cc = (akh >> 3) + c;
                int off = am * 32 + ((cc ^ (am & 3)) << 3);
                *(s16x8*)&Ahi[off] = hi;
                *(s16x8*)&Alo[off] = lo;
            }
        }
#pragma unroll
        for (int p = 0; p < 2; ++p) {
            int c = p * 2 + bc0;
            const float* r1 = wbase + (size_t)(k0 + c * 8) * HDIM;
            s16x8 h1, l1;
#pragma unroll
            for (int j = 0; j < 8; ++j) {
                float f1 = r1[j * HDIM];
                unsigned short a1 = bf16_rne(f1);
                h1[j] = (short)a1;
                l1[j] = (short)bf16_rne(f1 - bf16_up(a1));
            }
            int off = bn * 32 + ((c ^ (bn & 3)) << 3);
            *(s16x8*)&Bhi[off] = h1;
            *(s16x8*)&Blo[off] = l1;
        }
        __syncthreads();
        s16x8 ah[4], al[4];
#pragma unroll
        for (int fm = 0; fm < 4; ++fm) {
            int r = wr * 64 + fm * 16 + lr;
            int off = r * 32 + ((kg ^ (r & 3)) << 3);
            ah[fm] = *(const s16x8*)&Ahi[off];
            al[fm] = *(const s16x8*)&Alo[off];
        }
#pragma unroll
        for (int fn = 0; fn < 4; ++fn) {
            int cix = wc * 64 + fn * 16 + lr;
            int off = cix * 32 + ((kg ^ (cix & 3)) << 3);
            s16x8 bh = *(const s16x8*)&Bhi[off];
            s16x8 bl = *(const s16x8*)&Blo[off];
#pragma unroll
            for (int fm = 0; fm < 4; ++fm) {
                acc[fm][fn] = __builtin_amdgcn_mfma_f32_16x16x32_bf16(ah[fm], bh, acc[fm][fn], 0, 0, 0);
                acc[fm][fn] = __builtin_amdgcn_mfma_f32_16x16x32_bf16(ah[fm], bl, acc[fm][fn], 0, 0, 0);
                acc[fm][fn] = __builtin_amdgcn_mfma_f32_16x16x32_bf16(al[fm], bh, acc[fm][fn], 0, 0, 0);
            }
        }
        __syncthreads();
    }
#pragma unroll
    for (int fm = 0; fm < 4; ++fm) {
        int mbase = wr * 64 + fm * 16 + kg * 4;
#pragma unroll
        for (int r = 0; r < 4; ++r) {
            int m = mbase + r;
#pragma unroll
            for (int fn = 0; fn < 4; ++fn) {
                int col = n0 + wc * 64 + fn * 16 + lr;
                if (ROUTED) {
                    int p = pk[m];
                    if (p < 0) continue;
                    atomicAdd(&out[(size_t)(p >> 2) * HDIM + col], wts[m] * acc[fm][fn][r]);
                } else {
                    out[(size_t)(m0 + m) * HDIM + col] = acc[fm][fn][r];
                }
            }
        }
    }
}

// ---------------------------------------------------------------------------
extern "C" void kernel_launch(void* const* d_in, const int* in_sizes, int n_in,
                              void* d_out, int out_size, void* d_ws, size_t ws_size,
                              hipStream_t stream) {
    const float* x  = (const float*)d_in[0];
    const float* gw = (const float*)d_in[1];
    const float* Wg = (const float*)d_in[2];
    const float* Wu = (const float*)d_in[3];
    const float* Wd = (const float*)d_in[4];
    const float* sg = (const float*)d_in[5];
    const float* su = (const float*)d_in[6];
    const float* sd = (const float*)d_in[7];
    float* out = (float*)d_out;
    char* ws = (char*)d_ws;

    if (ws_size >= FAST_NEED) {
        int* cnt   = (int*)(ws + O_CNT);
        int* tok   = (int*)(ws + O_TOK);
        float* wgt = (float*)(ws + O_WGT);
        unsigned short* xh  = (unsigned short*)(ws + O_XH);
        unsigned short* xl  = (unsigned short*)(ws + O_XL);
        unsigned short* wgh = (unsigned short*)(ws + O_WG_H);
        unsigned short* wgl = (unsigned short*)(ws + O_WG_L);
        unsigned short* wuh = (unsigned short*)(ws + O_WU_H);
        unsigned short* wul = (unsigned short*)(ws + O_WU_L);
        unsigned short* wdh = (unsigned short*)(ws + O_WD_H);
        unsigned short* wdl = (unsigned short*)(ws + O_WD_L);
        unsigned short* hh  = (unsigned short*)(ws + O_HH);
        unsigned short* hl  = (unsigned short*)(ws + O_HL);

        hipMemsetAsync(cnt, 0, 128, stream);
        hipMemsetAsync(out, 0, (size_t)out_size * sizeof(float), stream);
        route_kernel<<<NTOK, 64, 0, stream>>>(x, gw, cnt, tok, wgt);
        conv_act<<<NTOK, 256, 0, stream>>>(x, xh, xl, cnt, tok, wgt);
        conv_w<<<dim3(16, 4, 17), 256, 0, stream>>>(Wg, sg, wgh, wgl, 1024, 512);
        conv_w<<<dim3(16, 4, 17), 256, 0, stream>>>(Wu, su, wuh, wul, 1024, 512);
        conv_w<<<dim3(8, 8, 17), 256, 0, stream>>>(Wd, sd, wdh, wdl, 512, 1024);
        moe_gemm<true><<<dim3(17, 16, 8), 256, 0, stream>>>(
            xh, xl, wgh, wgl, wuh, wul, cnt, tok, wgt, hh, hl, nullptr);
        moe_gemm<false><<<dim3(17, 16, 16), 256, 0, stream>>>(
            hh, hl, wdh, wdl, nullptr, nullptr, cnt, tok, wgt, nullptr, nullptr, out);
    } else {
        int* cnt   = (int*)(ws + FB_CNT_OFF);
        int* tok   = (int*)(ws + FB_TOK_OFF);
        float* wgt = (float*)(ws + FB_WGT_OFF);
        float* hs  = (float*)(ws + FB_HS_OFF);
        float* hr  = (float*)(ws + FB_HR_OFF);

        hipMemsetAsync(cnt, 0, NEXP * sizeof(int), stream);
        route_kernel<<<NTOK, 64, 0, stream>>>(x, gw, cnt, tok, wgt);
        fb_up<false><<<dim3(NTOK / 128, IDIM / 128), 256, 0, stream>>>(x, sg, su, cnt, tok, hs);
        fb_down<false><<<dim3(NTOK / 128, HDIM / 128), 256, 0, stream>>>(hs, sd, cnt, tok, wgt, out);
        fb_up<true><<<dim3(NEXP, NTOK / 128, IDIM / 128), 256, 0, stream>>>(x, Wg, Wu, cnt, tok, hr);
        fb_down<true><<<dim3(NEXP, NTOK / 128, HDIM / 128), 256, 0, stream>>>(hr, Wd, cnt, tok, wgt, out);
    }
}

// Round 11
// 447.264 us; speedup vs baseline: 2.1381x; 1.2014x over previous
//
#include <hip/hip_runtime.h>
#include <math.h>

// Problem constants: B=2, S=1024 -> T=2048 tokens
#define HDIM 1024
#define IDIM 512
#define NEXP 16
#define TOPK 4
#define NTOK 2048
#define NSLOT (NTOK * TOPK)      // 8192 routed slots
#define HROWS (NSLOT + NTOK)     // + 2048 shared rows = 10240

typedef __attribute__((ext_vector_type(8))) short s16x8;   // 8 bf16 (MFMA operand)
typedef __attribute__((ext_vector_type(4))) float f32x4;
typedef __attribute__((ext_vector_type(4))) unsigned short u16x4;

__device__ inline unsigned short bf16_rne(float f) {
    unsigned int u = __float_as_uint(f);
    u += 0x7FFF + ((u >> 16) & 1);
    return (unsigned short)(u >> 16);
}
__device__ inline float bf16_up(unsigned short h) {
    return __uint_as_float(((unsigned int)h) << 16);
}
// 16B-chunk XOR swizzle within a 32-elem row group; involution, <=2-way banks.
__device__ inline int swz4(int n) { return (n & 3) ^ ((n >> 2) & 3); }

// async global->LDS, 16B per lane (dest = wave-uniform base + lane*16;
// SOURCE address is per-lane -> row-gather + pre-swizzled source is legal)
typedef __attribute__((address_space(3))) unsigned int lds_uint_t;
typedef __attribute__((address_space(1))) unsigned int glob_uint_t;
#define GLD16(gsrc, ldst) __builtin_amdgcn_global_load_lds( \
    (const glob_uint_t*)(gsrc), (lds_uint_t*)(ldst), 16, 0, 0)

// ===========================================================================
// FAST-PATH workspace layout (bf16 hi/lo planes, 17 "experts": 16 routed +
// shared). Total ~130.3 MiB; gated on ws_size at launch.
// ===========================================================================
#define PLANE_W  ((size_t)17 * 512 * 1024)        // elems per weight plane
#define O_CNT    ((size_t)0)                      // int[17] (memset 128B)
#define O_TOK    ((size_t)256)                    // int[17*2048]
#define O_WGT    (O_TOK + (size_t)17 * NTOK * 4)
#define O_XH     (O_WGT + (size_t)17 * NTOK * 4)  // ushort[2048*1024]
#define O_XL     (O_XH + (size_t)NTOK * HDIM * 2)
#define O_WG_H   (O_XL + (size_t)NTOK * HDIM * 2)
#define O_WG_L   (O_WG_H + PLANE_W * 2)
#define O_WU_H   (O_WG_L + PLANE_W * 2)
#define O_WU_L   (O_WU_H + PLANE_W * 2)
#define O_WD_H   (O_WU_L + PLANE_W * 2)
#define O_WD_L   (O_WD_H + PLANE_W * 2)
#define O_HH     (O_WD_L + PLANE_W * 2)           // ushort[10240*512]
#define O_HL     (O_HH + (size_t)HROWS * IDIM * 2)
#define FAST_NEED (O_HL + (size_t)HROWS * IDIM * 2)

// ===========================================================================
// Routing: sigmoid(x@gw^T), top-4, normalize, per-expert lists.
// ===========================================================================
__global__ __launch_bounds__(64) void route_kernel(const float* __restrict__ x,
                                                   const float* __restrict__ gw,
                                                   int* __restrict__ cnt,
                                                   int* __restrict__ tok,
                                                   float* __restrict__ wgt) {
    const int t = blockIdx.x;
    const int lane = threadIdx.x;
    const float* xr = x + (size_t)t * HDIM;

    float acc[NEXP];
#pragma unroll
    for (int e = 0; e < NEXP; ++e) acc[e] = 0.f;
    for (int h = lane; h < HDIM; h += 64) {
        float xv = xr[h];
#pragma unroll
        for (int e = 0; e < NEXP; ++e) acc[e] += xv * gw[e * HDIM + h];
    }
#pragma unroll
    for (int e = 0; e < NEXP; ++e) {
        float v = acc[e];
#pragma unroll
        for (int off = 32; off > 0; off >>= 1) v += __shfl_xor(v, off, 64);
        acc[e] = v;
    }
    if (lane == 0) {
        float s[NEXP];
#pragma unroll
        for (int e = 0; e < NEXP; ++e) s[e] = 1.f / (1.f + expf(-acc[e]));
        bool used[NEXP];
#pragma unroll
        for (int e = 0; e < NEXP; ++e) used[e] = false;
        int id4[TOPK]; float w4[TOPK]; float sum = 0.f;
        for (int k = 0; k < TOPK; ++k) {
            float best = -1.f; int bi = 0;
            for (int e = 0; e < NEXP; ++e)
                if (!used[e] && s[e] > best) { best = s[e]; bi = e; }
            used[bi] = true; id4[k] = bi; w4[k] = best; sum += best;
        }
        float inv = 1.f / sum;
        for (int k = 0; k < TOPK; ++k) {
            int e = id4[k];
            int slot = atomicAdd(&cnt[e], 1);
            tok[e * NTOK + slot] = (t << 2) | k;
            wgt[e * NTOK + slot] = w4[k] * inv;
        }
    }
}

// ===========================================================================
// FAST PATH
// ===========================================================================

// ---- x -> bf16 hi/lo planes (LINEAR layout); init shared-expert routing ----
__global__ __launch_bounds__(256) void conv_act(const float* __restrict__ x,
                                                unsigned short* __restrict__ xh,
                                                unsigned short* __restrict__ xl,
                                                int* __restrict__ cnt,
                                                int* __restrict__ tok,
                                                float* __restrict__ wgt) {
    const int t = blockIdx.x;
    const int tid = threadIdx.x;
    if (tid == 0) {
        tok[16 * NTOK + t] = (t << 2);
        wgt[16 * NTOK + t] = 1.0f;
        if (t == 0) cnt[16] = NTOK;
    }
    const float* src = x + (size_t)t * HDIM;
    unsigned short* dh = xh + (size_t)t * HDIM;
    unsigned short* dl = xl + (size_t)t * HDIM;
    int i = tid * 4;
    f32x4 v = *(const f32x4*)(src + i);
    u16x4 hv, lv;
#pragma unroll
    for (int j = 0; j < 4; ++j) {
        unsigned short h = bf16_rne(v[j]);
        hv[j] = h;
        lv[j] = bf16_rne(v[j] - bf16_up(h));
    }
    *(u16x4*)(dh + i) = hv;
    *(u16x4*)(dl + i) = lv;
}

// ---- weight [K][N] -> transposed, chunk-swizzled bf16 hi/lo planes [n][k] --
// grid (K/64, N/128, 17); z==16 selects the shared-expert weight.
__global__ __launch_bounds__(256) void conv_w(const float* __restrict__ Wm,
                                              const float* __restrict__ Ws,
                                              unsigned short* __restrict__ dh,
                                              unsigned short* __restrict__ dl,
                                              int K, int N) {
    __shared__ float tile[64][129];
    const int k0 = blockIdx.x * 64, n0 = blockIdx.y * 128, z = blockIdx.z;
    const float* src = (z < 16) ? (Wm + (size_t)z * K * N) : Ws;
    const size_t dbase = (size_t)z * 512 * 1024;   // N*K identical for all mats
    const int tid = threadIdx.x;

#pragma unroll
    for (int i = 0; i < 8; ++i) {                  // 2048 vec4 loads, coalesced
        int v = tid + i * 256;
        int k = v >> 5, nv = v & 31;
        f32x4 t4 = *(const f32x4*)(src + (size_t)(k0 + k) * N + n0 + nv * 4);
#pragma unroll
        for (int j = 0; j < 4; ++j) tile[k][nv * 4 + j] = t4[j];
    }
    __syncthreads();
#pragma unroll
    for (int i = 0; i < 4; ++i) {                  // 1024 output chunks of 8
        int c = tid + i * 256;
        int n = c >> 3, dc = c & 7;
        int tl = dc >> 2, kg = dc & 3;
        int ng = n0 + n;
        s16x8 hv, lv;
#pragma unroll
        for (int j = 0; j < 8; ++j) {
            float f = tile[tl * 32 + kg * 8 + j][n];
            unsigned short h = bf16_rne(f);
            hv[j] = (short)h;
            lv[j] = (short)bf16_rne(f - bf16_up(h));
        }
        size_t off = dbase + (size_t)ng * K + k0 + tl * 32 + ((kg ^ swz4(ng)) << 3);
        *(s16x8*)(dh + off) = hv;
        *(s16x8*)(dl + off) = lv;
    }
}

// ---- grouped GEMM: tile 128m x 64n, BK=32, 4 waves (2x2), wave 64x32 -------
// Both A and B staged into double-buffered LDS via global_load_lds.
// A source is per-lane row-gathered with the chunk swizzle applied at the
// source address (A planes stored linear); B planes are pre-swizzled.
// XCD-affinity grid: bid&7 ~ XCD. Routed expert e -> XCD e%8 (4MB B fits L2);
// shared expert (e16) split by n across XCDs and scheduled first.
template<bool UP>
__global__ __launch_bounds__(256, 2) void moe_gemm(
        const unsigned short* __restrict__ Ah, const unsigned short* __restrict__ Al,
        const unsigned short* __restrict__ B1h, const unsigned short* __restrict__ B1l,
        const unsigned short* __restrict__ B2h, const unsigned short* __restrict__ B2l,
        const int* __restrict__ cnt, const int* __restrict__ tok,
        const float* __restrict__ wgt,
        unsigned short* __restrict__ Hh, unsigned short* __restrict__ Hl,
        float* __restrict__ out) {
    constexpr int KD = UP ? HDIM : IDIM;
    constexpr int NT = KD / 32;
    constexpr int NP = UP ? 4 : 2;                 // B planes staged

    // ---- XCD-affinity decode (perf heuristic only; correctness-independent)
    const int bid = blockIdx.x;
    const int xcd = bid & 7, s = bid >> 3;
    int e, m0, n0;
    if (UP) {
        if (s < 16) { e = 16; m0 = s * 128; n0 = xcd * 64; }
        else {
            int s2 = s - 16;
            e = (s2 >> 7) * 8 + xcd;
            int j = s2 & 127;
            m0 = (j >> 3) * 128; n0 = (j & 7) * 64;
        }
    } else {
        if (s < 32) { e = 16; m0 = (s >> 1) * 128; n0 = ((s & 1) * 8 + xcd) * 64; }
        else {
            int s2 = s - 32;
            e = (s2 >> 8) * 8 + xcd;
            int j = s2 & 255;
            m0 = (j >> 4) * 128; n0 = (j & 15) * 64;
        }
    }
    const int nt = cnt[e];
    if (m0 >= nt) return;

    __shared__ unsigned short Ab[2][2][128 * 32];  // 32 KB (hi/lo planes)
    __shared__ unsigned short Bb[2][NP][64 * 32];  // UP 32 KB / DOWN 16 KB
    __shared__ int pk[128];
    __shared__ float wts[128];

    const int tid = threadIdx.x;
    for (int i = tid; i < 128; i += 256) {
        int ss = m0 + i;
        pk[i] = (ss < nt) ? tok[e * NTOK + ss] : -1;
        wts[i] = (ss < nt) ? wgt[e * NTOK + ss] : 0.f;
    }
    __syncthreads();

    const int lane = tid & 63, wid = tid >> 6;
    const int wr = wid >> 1, wc = wid & 1;
    const int lr = lane & 15, kg = lane >> 4;

    // ---- A staging roles: thread stages chunks (r0,kgl) and (r0+64,kgl).
    const int r0 = tid >> 2;
    const int kgl = tid & 3;
    const unsigned short* sA[2][2];
    int skoff[2];
#pragma unroll
    for (int i = 0; i < 2; ++i) {
        int r = r0 + i * 64;
        int p = pk[r];
        size_t row;
        if (UP) row = (p >= 0) ? (size_t)(p >> 2) : 0;
        else    row = (p < 0) ? 0 : (size_t)((e == 16) ? (NSLOT + (p >> 2)) : p);
        sA[i][0] = Ah + row * KD;
        sA[i][1] = Al + row * KD;
        skoff[i] = (kgl ^ swz4(r)) << 3;           // source chunk permute
    }

    // ---- B staging source (pre-transposed, pre-swizzled planes)
    const size_t eoff = (size_t)e * 512 * 1024;
    const unsigned short* bp[4];
    bp[0] = B1h + eoff;
    bp[1] = B1l + eoff;
    if (UP) { bp[2] = B2h + eoff; bp[3] = B2l + eoff; }
    const size_t soff = (size_t)(n0 + (tid >> 2)) * KD + ((tid & 3) << 3);

    f32x4 acc1[4][2], acc2[4][2];
#pragma unroll
    for (int i = 0; i < 4; ++i)
#pragma unroll
        for (int j = 0; j < 2; ++j) {
            acc1[i][j] = (f32x4){0.f, 0.f, 0.f, 0.f};
            if (UP) acc2[i][j] = (f32x4){0.f, 0.f, 0.f, 0.f};
        }

#define STAGE(buf, k0)                                                        \
    {                                                                         \
        _Pragma("unroll")                                                     \
        for (int i = 0; i < 2; ++i) {                                         \
            GLD16(sA[i][0] + (k0) + skoff[i], &Ab[buf][0][(tid + i * 256) << 3]); \
            GLD16(sA[i][1] + (k0) + skoff[i], &Ab[buf][1][(tid + i * 256) << 3]); \
        }                                                                     \
        _Pragma("unroll")                                                     \
        for (int pl = 0; pl < NP; ++pl)                                       \
            GLD16(bp[pl] + soff + (k0), &Bb[buf][pl][tid << 3]);              \
    }

#define COMPUTE(buf)                                                              \
    {                                                                             \
        s16x8 ah[4], al[4];                                                       \
        _Pragma("unroll")                                                         \
        for (int fm = 0; fm < 4; ++fm) {                                          \
            int m = wr * 64 + fm * 16 + lr;                                       \
            int aoff = (m << 5) + ((kg ^ swz4(m)) << 3);                          \
            ah[fm] = *(const s16x8*)&Ab[buf][0][aoff];                            \
            al[fm] = *(const s16x8*)&Ab[buf][1][aoff];                            \
        }                                                                         \
        _Pragma("unroll")                                                         \
        for (int fn = 0; fn < 2; ++fn) {                                          \
            int nl = wc * 32 + fn * 16 + lr;                                      \
            int off = (nl << 5) + ((kg ^ swz4(nl)) << 3);                         \
            s16x8 b1h = *(const s16x8*)&Bb[buf][0][off];                          \
            s16x8 b1l = *(const s16x8*)&Bb[buf][1][off];                          \
            _Pragma("unroll")                                                     \
            for (int fm = 0; fm < 4; ++fm) {                                      \
                acc1[fm][fn] = __builtin_amdgcn_mfma_f32_16x16x32_bf16(           \
                    ah[fm], b1h, acc1[fm][fn], 0, 0, 0);                          \
                acc1[fm][fn] = __builtin_amdgcn_mfma_f32_16x16x32_bf16(           \
                    ah[fm], b1l, acc1[fm][fn], 0, 0, 0);                          \
                acc1[fm][fn] = __builtin_amdgcn_mfma_f32_16x16x32_bf16(           \
                    al[fm], b1h, acc1[fm][fn], 0, 0, 0);                          \
            }                                                                     \
            if (UP) {                                                             \
                s16x8 b2h = *(const s16x8*)&Bb[buf][NP - 2][off];                 \
                s16x8 b2l = *(const s16x8*)&Bb[buf][NP - 1][off];                 \
                _Pragma("unroll")                                                 \
                for (int fm = 0; fm < 4; ++fm) {                                  \
                    acc2[fm][fn] = __builtin_amdgcn_mfma_f32_16x16x32_bf16(       \
                        ah[fm], b2h, acc2[fm][fn], 0, 0, 0);                      \
                    acc2[fm][fn] = __builtin_amdgcn_mfma_f32_16x16x32_bf16(       \
                        ah[fm], b2l, acc2[fm][fn], 0, 0, 0);                      \
                    acc2[fm][fn] = __builtin_amdgcn_mfma_f32_16x16x32_bf16(       \
                        al[fm], b2h, acc2[fm][fn], 0, 0, 0);                      \
                }                                                                 \
            }                                                                     \
        }                                                                         \
    }

    // stage-before-compute double-buffered loop: loads for t+1 fly during
    // COMPUTE(t); the pre-barrier drain has the MFMA phase to cover them.
    STAGE(0, 0);
    __syncthreads();
    int cur = 0;
    for (int t = 0; t < NT - 1; ++t) {
        STAGE(cur ^ 1, (t + 1) * 32);
        COMPUTE(cur);
        __syncthreads();
        cur ^= 1;
    }
    COMPUTE(cur);

#undef STAGE
#undef COMPUTE

    // ---- epilogue
#pragma unroll
    for (int fm = 0; fm < 4; ++fm) {
#pragma unroll
        for (int r = 0; r < 4; ++r) {
            int m = wr * 64 + fm * 16 + kg * 4 + r;
            int p = pk[m];
            if (p < 0) continue;
            if (UP) {
                size_t hrow = (e == 16) ? (size_t)(NSLOT + (p >> 2)) : (size_t)p;
#pragma unroll
                for (int fn = 0; fn < 2; ++fn) {
                    int col = n0 + wc * 32 + fn * 16 + lr;
                    float g = acc1[fm][fn][r], u = acc2[fm][fn][r];
                    float v = (g / (1.f + expf(-g))) * u;
                    unsigned short h = bf16_rne(v);
                    Hh[hrow * IDIM + col] = h;
                    Hl[hrow * IDIM + col] = bf16_rne(v - bf16_up(h));
                }
            } else {
                int tkn = p >> 2;
                float w = wts[m];
#pragma unroll
                for (int fn = 0; fn < 2; ++fn) {
                    int col = n0 + wc * 32 + fn * 16 + lr;
                    atomicAdd(&out[(size_t)tkn * HDIM + col], w * acc1[fm][fn][r]);
                }
            }
        }
    }
}

// ===========================================================================
// FALLBACK PATH (round-4 kernels, verified passing): used if ws too small.
// ===========================================================================
#define FB_CNT_OFF   0
#define FB_TOK_OFF   256
#define FB_WGT_OFF   (FB_TOK_OFF + NEXP * NTOK * 4)
#define FB_HS_OFF    (FB_WGT_OFF + NEXP * NTOK * 4)
#define FB_HR_OFF    (FB_HS_OFF + NTOK * IDIM * 4)

template<bool ROUTED>
__global__ __launch_bounds__(256) void fb_up(const float* __restrict__ A,
                                             const float* __restrict__ W1,
                                             const float* __restrict__ W2,
                                             const int* __restrict__ cnt,
                                             const int* __restrict__ tok,
                                             float* __restrict__ Hout) {
    int e = 0, nt = NTOK, m0, n0;
    if (ROUTED) {
        e = blockIdx.x; nt = cnt[e]; m0 = blockIdx.y * 128;
        if (m0 >= nt) return;
        n0 = blockIdx.z * 128;
    } else { m0 = blockIdx.x * 128; n0 = blockIdx.y * 128; }

    __shared__ unsigned short Ahi[128 * 32], Alo[128 * 32];
    __shared__ unsigned short B1hi[128 * 32], B1lo[128 * 32];
    __shared__ unsigned short B2hi[128 * 32], B2lo[128 * 32];
    __shared__ int pk[128];
    const int tid = threadIdx.x;
    if (ROUTED) {
        for (int i = tid; i < 128; i += 256) {
            int s = m0 + i;
            pk[i] = (s < nt) ? tok[e * NTOK + s] : -1;
        }
        __syncthreads();
    }
    const int am = tid >> 1;
    const int akh = (tid & 1) << 4;
    int arow;
    if (ROUTED) { int p = pk[am]; arow = (p >= 0) ? (p >> 2) : -1; }
    else arow = m0 + am;
    const float* aptr = (arow >= 0) ? (A + (size_t)arow * HDIM + akh) : (const float*)0;
    const int bn = tid & 127;
    const int bc0 = tid >> 7;
    const size_t eoffB = ROUTED ? (size_t)e * HDIM * IDIM : 0;
    const float* w1base = W1 + eoffB + n0 + bn;
    const float* w2base = W2 + eoffB + n0 + bn;
    const int lane = tid & 63, wid = tid >> 6;
    const int wr = wid >> 1, wc = wid & 1;
    const int lr = lane & 15, kg = lane >> 4;
    f32x4 accg[4][4], accu[4][4];
#pragma unroll
    for (int i = 0; i < 4; ++i)
#pragma unroll
        for (int j = 0; j < 4; ++j) {
            accg[i][j] = (f32x4){0.f, 0.f, 0.f, 0.f};
            accu[i][j] = (f32x4){0.f, 0.f, 0.f, 0.f};
        }
    for (int k0 = 0; k0 < HDIM; k0 += 32) {
        {
            float v[16];
            if (arow >= 0) {
                const f32x4* p = (const f32x4*)(aptr + k0);
#pragma unroll
                for (int q = 0; q < 4; ++q) { f32x4 t4 = p[q];
#pragma unroll
                    for (int j = 0; j < 4; ++j) v[q * 4 + j] = t4[j]; }
            } else {
#pragma unroll
                for (int q = 0; q < 16; ++q) v[q] = 0.f;
            }
#pragma unroll
            for (int c = 0; c < 2; ++c) {
                s16x8 hi, lo;
#pragma unroll
                for (int j = 0; j < 8; ++j) {
                    float f = v[c * 8 + j];
                    unsigned short h = bf16_rne(f);
                    hi[j] = (short)h;
                    lo[j] = (short)bf16_rne(f - bf16_up(h));
                }
                int cc = (akh >> 3) + c;
                int off = am * 32 + ((cc ^ (am & 3)) << 3);
                *(s16x8*)&Ahi[off] = hi;
                *(s16x8*)&Alo[off] = lo;
            }
        }
#pragma unroll
        for (int p = 0; p < 2; ++p) {
            int c = p * 2 + bc0;
            const float* r1 = w1base + (size_t)(k0 + c * 8) * IDIM;
            const float* r2 = w2base + (size_t)(k0 + c * 8) * IDIM;
            s16x8 h1, l1, h2, l2;
#pragma unroll
            for (int j = 0; j < 8; ++j) {
                float f1 = r1[j * IDIM];
                unsigned short a1 = bf16_rne(f1);
                h1[j] = (short)a1;
                l1[j] = (short)bf16_rne(f1 - bf16_up(a1));
                float f2 = r2[j * IDIM];
                unsigned short a2 = bf16_rne(f2);
                h2[j] = (short)a2;
                l2[j] = (short)bf16_rne(f2 - bf16_up(a2));
            }
            int off = bn * 32 + ((c ^ (bn & 3)) << 3);
            *(s16x8*)&B1hi[off] = h1;
            *(s16x8*)&B1lo[off] = l1;
            *(s16x8*)&B2hi[off] = h2;
            *(s16x8*)&B2lo[off] = l2;
        }
        __syncthreads();
        s16x8 ah[4], al[4];
#pragma unroll
        for (int fm = 0; fm < 4; ++fm) {
            int r = wr * 64 + fm * 16 + lr;
            int off = r * 32 + ((kg ^ (r & 3)) << 3);
            ah[fm] = *(const s16x8*)&Ahi[off];
            al[fm] = *(const s16x8*)&Alo[off];
        }
#pragma unroll
        for (int fn = 0; fn < 4; ++fn) {
            int cix = wc * 64 + fn * 16 + lr;
            int off = cix * 32 + ((kg ^ (cix & 3)) << 3);
            s16x8 b1h = *(const s16x8*)&B1hi[off];
            s16x8 b1l = *(const s16x8*)&B1lo[off];
            s16x8 b2h = *(const s16x8*)&B2hi[off];
            s16x8 b2l = *(const s16x8*)&B2lo[off];
#pragma unroll
            for (int fm = 0; fm < 4; ++fm) {
                accg[fm][fn] = __builtin_amdgcn_mfma_f32_16x16x32_bf16(ah[fm], b1h, accg[fm][fn], 0, 0, 0);
                accg[fm][fn] = __builtin_amdgcn_mfma_f32_16x16x32_bf16(ah[fm], b1l, accg[fm][fn], 0, 0, 0);
                accg[fm][fn] = __builtin_amdgcn_mfma_f32_16x16x32_bf16(al[fm], b1h, accg[fm][fn], 0, 0, 0);
                accu[fm][fn] = __builtin_amdgcn_mfma_f32_16x16x32_bf16(ah[fm], b2h, accu[fm][fn], 0, 0, 0);
                accu[fm][fn] = __builtin_amdgcn_mfma_f32_16x16x32_bf16(ah[fm], b2l, accu[fm][fn], 0, 0, 0);
                accu[fm][fn] = __builtin_amdgcn_mfma_f32_16x16x32_bf16(al[fm], b2h, accu[fm][fn], 0, 0, 0);
            }
        }
        __syncthreads();
    }
#pragma unroll
    for (int fm = 0; fm < 4; ++fm) {
        int mbase = wr * 64 + fm * 16 + kg * 4;
#pragma unroll
        for (int r = 0; r < 4; ++r) {
            int m = mbase + r;
            int orow;
            if (ROUTED) { int p = pk[m]; if (p < 0) continue; orow = p; }
            else orow = m0 + m;
#pragma unroll
            for (int fn = 0; fn < 4; ++fn) {
                float g = accg[fm][fn][r], u = accu[fm][fn][r];
                float sil = g / (1.f + expf(-g));
                Hout[(size_t)orow * IDIM + n0 + wc * 64 + fn * 16 + lr] = sil * u;
            }
        }
    }
}

template<bool ROUTED>
__global__ __launch_bounds__(256) void fb_down(const float* __restrict__ Hin,
                                               const float* __restrict__ Wdn,
                                               const int* __restrict__ cnt,
                                               const int* __restrict__ tok,
                                               const float* __restrict__ wgt,
                                               float* __restrict__ out) {
    int e = 0, nt = NTOK, m0, n0;
    if (ROUTED) {
        e = blockIdx.x; nt = cnt[e]; m0 = blockIdx.y * 128;
        if (m0 >= nt) return;
        n0 = blockIdx.z * 128;
    } else { m0 = blockIdx.x * 128; n0 = blockIdx.y * 128; }

    __shared__ unsigned short Ahi[128 * 32], Alo[128 * 32];
    __shared__ unsigned short Bhi[128 * 32], Blo[128 * 32];
    __shared__ int pk[128];
    __shared__ float wts[128];
    const int tid = threadIdx.x;
    if (ROUTED) {
        for (int i = tid; i < 128; i += 256) {
            int s = m0 + i;
            pk[i] = (s < nt) ? tok[e * NTOK + s] : -1;
            wts[i] = (s < nt) ? wgt[e * NTOK + s] : 0.f;
        }
        __syncthreads();
    }
    const int am = tid >> 1;
    const int akh = (tid & 1) << 4;
    int arow;
    if (ROUTED) arow = pk[am];
    else arow = m0 + am;
    const float* aptr = (arow >= 0) ? (Hin + (size_t)arow * IDIM + akh) : (const float*)0;
    const int bn = tid & 127;
    const int bc0 = tid >> 7;
    const size_t eoffB = ROUTED ? (size_t)e * IDIM * HDIM : 0;
    const float* wbase = Wdn + eoffB + n0 + bn;
    const int lane = tid & 63, wid = tid >> 6;
    const int wr = wid >> 1, wc = wid & 1;
    const int lr = lane & 15, kg = lane >> 4;
    f32x4 acc[4][4];
#pragma unroll
    for (int i = 0; i < 4; ++i)
#pragma unroll
        for (int j = 0; j < 4; ++j) acc[i][j] = (f32x4){0.f, 0.f, 0.f, 0.f};
    for (int k0 = 0; k0 < IDIM; k0 += 32) {
        {
            float v[16];
            if (arow >= 0) {
                const f32x4* p = (const f32x4*)(aptr + k0);
#pragma unroll
                for (int q = 0; q < 4; ++q) { f32x4 t4 = p[q];
#pragma unroll
                    for (int j = 0; j < 4; ++j) v[q * 4 + j] = t4[j]; }
            } else {
#pragma unroll
                for (int q = 0; q < 16; ++q) v[q] = 0.f;
            }
#pragma unroll
            for (int c = 0; c < 2; ++c) {
                s16x8 hi, lo;
#pragma unroll
                for (int j = 0; j < 8; ++j) {
                    float f = v[c * 8 + j];
                    unsigned short h = bf16_rne(f);
                    hi[j] = (short)h;
                    lo[j] = (short)bf16_rne(f - bf16_up(h));
                }
                int cc = (akh >> 3) + c;
                int off = am * 32 + ((cc ^ (am & 3)) << 3);
                *(s16x8*)&Ahi[off] = hi;
                *(s16x8*)&Alo[off] = lo;
            }
        }
#pragma unroll
        for (int p = 0; p < 2; ++p) {
            int c = p * 2 + bc0;
            const float* r1 = wbase + (size_t)(k0 + c * 8) * HDIM;
            s16x8 h1, l1;
#pragma unroll
            for (int j = 0; j < 8; ++j) {
                float f1 = r1[j * HDIM];
                unsigned short a1 = bf16_rne(f1);
                h1[j] = (short)a1;
                l1[j] = (short)bf16_rne(f1 - bf16_up(a1));
            }
            int off = bn * 32 + ((c ^ (bn & 3)) << 3);
            *(s16x8*)&Bhi[off] = h1;
            *(s16x8*)&Blo[off] = l1;
        }
        __syncthreads();
        s16x8 ah[4], al[4];
#pragma unroll
        for (int fm = 0; fm < 4; ++fm) {
            int r = wr * 64 + fm * 16 + lr;
            int off = r * 32 + ((kg ^ (r & 3)) << 3);
            ah[fm] = *(const s16x8*)&Ahi[off];
            al[fm] = *(const s16x8*)&Alo[off];
        }
#pragma unroll
        for (int fn = 0; fn < 4; ++fn) {
            int cix = wc * 64 + fn * 16 + lr;
            int off = cix * 32 + ((kg ^ (cix & 3)) << 3);
            s16x8 bh = *(const s16x8*)&Bhi[off];
            s16x8 bl = *(const s16x8*)&Blo[off];
#pragma unroll
            for (int fm = 0; fm < 4; ++fm) {
                acc[fm][fn] = __builtin_amdgcn_mfma_f32_16x16x32_bf16(ah[fm], bh, acc[fm][fn], 0, 0, 0);
                acc[fm][fn] = __builtin_amdgcn_mfma_f32_16x16x32_bf16(ah[fm], bl, acc[fm][fn], 0, 0, 0);
                acc[fm][fn] = __builtin_amdgcn_mfma_f32_16x16x32_bf16(al[fm], bh, acc[fm][fn], 0, 0, 0);
            }
        }
        __syncthreads();
    }
#pragma unroll
    for (int fm = 0; fm < 4; ++fm) {
        int mbase = wr * 64 + fm * 16 + kg * 4;
#pragma unroll
        for (int r = 0; r < 4; ++r) {
            int m = mbase + r;
#pragma unroll
            for (int fn = 0; fn < 4; ++fn) {
                int col = n0 + wc * 64 + fn * 16 + lr;
                if (ROUTED) {
                    int p = pk[m];
                    if (p < 0) continue;
                    atomicAdd(&out[(size_t)(p >> 2) * HDIM + col], wts[m] * acc[fm][fn][r]);
                } else {
                    out[(size_t)(m0 + m) * HDIM + col] = acc[fm][fn][r];
                }
            }
        }
    }
}

// ---------------------------------------------------------------------------
extern "C" void kernel_launch(void* const* d_in, const int* in_sizes, int n_in,
                              void* d_out, int out_size, void* d_ws, size_t ws_size,
                              hipStream_t stream) {
    const float* x  = (const float*)d_in[0];
    const float* gw = (const float*)d_in[1];
    const float* Wg = (const float*)d_in[2];
    const float* Wu = (const float*)d_in[3];
    const float* Wd = (const float*)d_in[4];
    const float* sg = (const float*)d_in[5];
    const float* su = (const float*)d_in[6];
    const float* sd = (const float*)d_in[7];
    float* out = (float*)d_out;
    char* ws = (char*)d_ws;

    if (ws_size >= FAST_NEED) {
        int* cnt   = (int*)(ws + O_CNT);
        int* tok   = (int*)(ws + O_TOK);
        float* wgt = (float*)(ws + O_WGT);
        unsigned short* xh  = (unsigned short*)(ws + O_XH);
        unsigned short* xl  = (unsigned short*)(ws + O_XL);
        unsigned short* wgh = (unsigned short*)(ws + O_WG_H);
        unsigned short* wgl = (unsigned short*)(ws + O_WG_L);
        unsigned short* wuh = (unsigned short*)(ws + O_WU_H);
        unsigned short* wul = (unsigned short*)(ws + O_WU_L);
        unsigned short* wdh = (unsigned short*)(ws + O_WD_H);
        unsigned short* wdl = (unsigned short*)(ws + O_WD_L);
        unsigned short* hh  = (unsigned short*)(ws + O_HH);
        unsigned short* hl  = (unsigned short*)(ws + O_HL);

        hipMemsetAsync(cnt, 0, 128, stream);
        hipMemsetAsync(out, 0, (size_t)out_size * sizeof(float), stream);
        route_kernel<<<NTOK, 64, 0, stream>>>(x, gw, cnt, tok, wgt);
        conv_act<<<NTOK, 256, 0, stream>>>(x, xh, xl, cnt, tok, wgt);
        conv_w<<<dim3(16, 4, 17), 256, 0, stream>>>(Wg, sg, wgh, wgl, 1024, 512);
        conv_w<<<dim3(16, 4, 17), 256, 0, stream>>>(Wu, su, wuh, wul, 1024, 512);
        conv_w<<<dim3(8, 8, 17), 256, 0, stream>>>(Wd, sd, wdh, wdl, 512, 1024);
        // XCD-affinity 1-D grids: UP 8*(16+256)=2176, DOWN 8*(32+512)=4352
        moe_gemm<true><<<2176, 256, 0, stream>>>(
            xh, xl, wgh, wgl, wuh, wul, cnt, tok, wgt, hh, hl, nullptr);
        moe_gemm<false><<<4352, 256, 0, stream>>>(
            hh, hl, wdh, wdl, nullptr, nullptr, cnt, tok, wgt, nullptr, nullptr, out);
    } else {
        int* cnt   = (int*)(ws + FB_CNT_OFF);
        int* tok   = (int*)(ws + FB_TOK_OFF);
        float* wgt = (float*)(ws + FB_WGT_OFF);
        float* hs  = (float*)(ws + FB_HS_OFF);
        float* hr  = (float*)(ws + FB_HR_OFF);

        hipMemsetAsync(cnt, 0, NEXP * sizeof(int), stream);
        route_kernel<<<NTOK, 64, 0, stream>>>(x, gw, cnt, tok, wgt);
        fb_up<false><<<dim3(NTOK / 128, IDIM / 128), 256, 0, stream>>>(x, sg, su, cnt, tok, hs);
        fb_down<false><<<dim3(NTOK / 128, HDIM / 128), 256, 0, stream>>>(hs, sd, cnt, tok, wgt, out);
        fb_up<true><<<dim3(NEXP, NTOK / 128, IDIM / 128), 256, 0, stream>>>(x, Wg, Wu, cnt, tok, hr);
        fb_down<true><<<dim3(NEXP, NTOK / 128, HDIM / 128), 256, 0, stream>>>(hr, Wd, cnt, tok, wgt, out);
    }
}